// Round 8
// baseline (327.098 us; speedup 1.0000x reference)
//
#include <hip/hip_runtime.h>
#include <stdint.h>
#include <math.h>

#define NDIM 256
#define BATCH 65536
#define NROT 32640          // 256*255/2

typedef float  f32x4 __attribute__((ext_vector_type(4)));
typedef short  s16x8 __attribute__((ext_vector_type(8)));
typedef unsigned int u32x4 __attribute__((ext_vector_type(4)));
typedef unsigned int u32x2 __attribute__((ext_vector_type(2)));

// round-to-nearest-even float -> bf16 bits
static __device__ __forceinline__ unsigned short f2bf(float f) {
    unsigned int u = __float_as_uint(f);
    u += 0x7fffu + ((u >> 16) & 1u);
    return (unsigned short)(u >> 16);
}

// nearest 4-aligned sweep boundary to k*(NROT/pblk); shared by k_blocks
// and k_combine (the block-diagonal skip logic depends on agreement).
static __device__ __forceinline__ int sweep_bound(int k, int pblk) {
    int target = k * (NROT / pblk);
    int best = 0, bd = 0x7fffffff;
    for (int i = 0; i <= 256; i += 4) {
        int pre = i * 255 - (i * (i - 1)) / 2;
        int d = pre - target; d = (d < 0) ? -d : d;
        if (d < bd) { bd = d; best = i; }
    }
    return best;
}

// ---------------- kernel 1: build pblk partial Givens products per matrix ---
// 4 sweeps fused (skewed schedule, order-equivalent: disjoint-row rotations
// commute). Active rows u0..u3 in registers. Hot loop touches ONLY LDS
// (R4 lesson). R7 lesson: DS completes in-order per wave, so ANY immediate-
// use LDS read drains the whole prefetch queue -> EVERYTHING a j-step
// consumes (row value + 4 angle pairs) is register-prefetched 8 steps ahead;
// waits then cover ops issued >=8 steps earlier only.
__global__ __launch_bounds__(64) void k_blocks(const float* __restrict__ r1,
                                               const float* __restrict__ r2,
                                               float* __restrict__ bmats, int pblk) {
    __shared__ float colb[264 * 64];
    __shared__ float2 csb[264 * 4];     // one group's steady angles, [jj][a] (+8 pad)
    __shared__ float2 tri[24 * 6];      // all groups' triangle angles
    const int t = threadIdx.x;          // column within chunk
    const int chunk = blockIdx.x;       // 0..3 (64 cols each)
    const int b = blockIdx.y;           // 0..pblk-1
    const int set = blockIdx.z;         // 0 = rots1, 1 = rots2
    const int col0 = chunk * 64;
    const float* rots = set ? r2 : r1;

    const int s0 = sweep_bound(b, pblk);
    const int s1 = sweep_bound(b + 1, pblk);
    const int ngroups = (s1 - s0) >> 2;

    // zero colb (incl. pad rows 256..263), set identity diagonal
    {
        const f32x4 z = {0.f, 0.f, 0.f, 0.f};
        #pragma unroll 11
        for (int q = 0; q < 66; q++)
            *(f32x4*)&colb[(q * 64 + t) * 4] = z;
        colb[(col0 + t) * 64 + t] = 1.0f;
    }

    // stage all triangle angles (6 per group) into LDS
    // q -> pair (a,bb): 0->(0,1) 1->(0,2) 2->(0,3) 3->(1,2) 4->(1,3) 5->(2,3)
    for (int k = t; k < ngroups * 6; k += 64) {
        int g = k / 6, q = k - g * 6;
        int a  = (q < 3) ? 0 : ((q < 5) ? 1 : 2);
        int bb = (q < 3) ? (q + 1) : ((q < 5) ? (q - 1) : 3);
        int m0 = s0 + g * 4;
        int m = m0 + a;
        int base = m * 255 - (m * (m - 1)) / 2;
        float th = rots[base - m - 1 + (m0 + bb)];
        float sv, cv; sincosf(th, &sv, &cv);
        tri[k] = make_float2(cv, sv);
    }
    // single-wave WG: DS pipe is in-order per wave, no barrier needed

    for (int g = 0; g < ngroups; g++) {
        const int m0 = s0 + g * 4;
        int off[4];
        #pragma unroll
        for (int a = 0; a < 4; a++) {
            int m = m0 + a;
            int base = m * 255 - (m * (m - 1)) / 2;
            off[a] = base - m - 1;                  // angle for (m,j) = rots[off[a]+j]
        }
        const int n_j = 252 - m0;                   // #j in [m0+4, 256)
        const int n_p = (n_j > 0) ? ((n_j + 7) & ~7) : 0;

        // stage steady angles with identity padding: csb[jj*4 + a]
        for (int k = t; k < n_p * 4; k += 64) {
            int jj = k >> 2, a = k & 3;
            int j = m0 + 4 + jj;
            if (j < 256) {
                float th = rots[off[a] + j];
                float sv, cv; sincosf(th, &sv, &cv);
                csb[k] = make_float2(cv, sv);
            } else {
                csb[k] = make_float2(1.f, 0.f);
            }
        }

        // active rows -> registers
        float u0 = colb[(m0 + 0) * 64 + t];
        float u1 = colb[(m0 + 1) * 64 + t];
        float u2 = colb[(m0 + 2) * 64 + t];
        float u3 = colb[(m0 + 3) * 64 + t];

        // triangle peel: (m0,m0+1..3), (m0+1,m0+2..3), (m0+2,m0+3)
        {
            float2 cv; float nr;
            cv = tri[g * 6 + 0]; nr = cv.y * u0 + cv.x * u1; u0 = cv.x * u0 - cv.y * u1; u1 = nr;
            cv = tri[g * 6 + 1]; nr = cv.y * u0 + cv.x * u2; u0 = cv.x * u0 - cv.y * u2; u2 = nr;
            cv = tri[g * 6 + 2]; nr = cv.y * u0 + cv.x * u3; u0 = cv.x * u0 - cv.y * u3; u3 = nr;
            cv = tri[g * 6 + 3]; nr = cv.y * u1 + cv.x * u2; u1 = cv.x * u1 - cv.y * u2; u2 = nr;
            cv = tri[g * 6 + 4]; nr = cv.y * u1 + cv.x * u3; u1 = cv.x * u1 - cv.y * u3; u3 = nr;
            cv = tri[g * 6 + 5]; nr = cv.y * u2 + cv.x * u3; u2 = cv.x * u2 - cv.y * u3; u3 = nr;
        }

        // steady state: guard-free unroll-8 body; rows AND angles prefetched
        // 8 steps deep so no use-site wait drains fresh DS ops.
        if (n_p > 0) {
            float rbuf[8];
            f32x4 ab01[8], ab23[8];
            #pragma unroll
            for (int p = 0; p < 8; p++) {
                rbuf[p] = colb[(m0 + 4 + p) * 64 + t];
                ab01[p] = *(const f32x4*)&csb[p * 4 + 0];
                ab23[p] = *(const f32x4*)&csb[p * 4 + 2];
            }
            for (int c = 0; c < n_p; c += 8) {
                #pragma unroll
                for (int p = 0; p < 8; p++) {
                    const int i = c + p;
                    const int j = m0 + 4 + i;
                    float r = rbuf[p];
                    f32x4 A01 = ab01[p], A23 = ab23[p];
                    // prefetch step i+8 (csb pad keeps reads in-bounds;
                    // values past n_p are never consumed)
                    int jn = j + 8; jn = (jn < 263) ? jn : 263;
                    rbuf[p] = colb[jn * 64 + t];
                    ab01[p] = *(const f32x4*)&csb[(i + 8) * 4 + 0];
                    ab23[p] = *(const f32x4*)&csb[(i + 8) * 4 + 2];
                    float nr;
                    nr = A01.y * u0 + A01.x * r; u0 = A01.x * u0 - A01.y * r; r = nr;
                    nr = A01.w * u1 + A01.z * r; u1 = A01.z * u1 - A01.w * r; r = nr;
                    nr = A23.y * u2 + A23.x * r; u2 = A23.x * u2 - A23.y * r; r = nr;
                    nr = A23.w * u3 + A23.z * r; u3 = A23.z * u3 - A23.w * r; r = nr;
                    colb[j * 64 + t] = r;
                }
            }
        }
        colb[(m0 + 0) * 64 + t] = u0;
        colb[(m0 + 1) * 64 + t] = u1;
        colb[(m0 + 2) * 64 + t] = u2;
        colb[(m0 + 3) * 64 + t] = u3;
    }

    float* outm = bmats + (size_t)(set * pblk + b) * 65536;
    for (int r = 0; r < 256; r++)
        outm[(size_t)r * 256 + col0 + t] = colb[r * 64 + t];
}

// ---------------- kernel 2: pairwise combine round (fp32 256^3 matmul) ------
// dst[p] = src[2p+1] @ src[2p]. A = src[2p+1] is identity above sweep s0A
// (block-diagonal) -> tiles with all rows < s0A are a copy of B; tiles with
// all rows >= s0A skip k-blocks below s0A. As padded to stride 36 to break
// the stride-32 4-way bank conflict on the column reads.
__global__ __launch_bounds__(256) void k_combine(const float* __restrict__ src,
                                                 float* __restrict__ dst,
                                                 int half, int pblk) {
    const int by = blockIdx.y;
    const int set = by / half, pidx = by % half;
    const int stride = pblk / (2 * half);
    const int s0A = sweep_bound((2 * pidx + 1) * stride, pblk);
    const float* Am = src + (size_t)(set * 2 * half + 2 * pidx + 1) * 65536;
    const float* Bm = src + (size_t)(set * 2 * half + 2 * pidx) * 65536;
    float* Dm = dst + (size_t)(set * half + pidx) * 65536;
    const int tr = blockIdx.x >> 2, tc = blockIdx.x & 3;
    const int tid = threadIdx.x;

    if (tr * 64 + 64 <= s0A) {                 // pure copy tile: D = B
        #pragma unroll
        for (int it = 0; it < 4; it++) {
            int flat = tid + it * 256;         // 64 rows x 16 float4
            int r = flat >> 4, c4 = flat & 15;
            size_t idx = (size_t)(tr * 64 + r) * 256 + tc * 64 + c4 * 4;
            *(f32x4*)&Dm[idx] = *(const f32x4*)&Bm[idx];
        }
        return;
    }
    const int kb0 = (tr * 64 >= s0A) ? (s0A >> 5) : 0;

    __shared__ float As[64 * 36];              // padded: stride 36
    __shared__ float Bs[32 * 64];
    const int tx = tid & 15, ty = tid >> 4;

    float acc[4][4] = {};
    for (int kb = kb0; kb < 8; kb++) {
        __syncthreads();
        #pragma unroll
        for (int it = 0; it < 2; it++) {       // A: 64x32 = 512 float4
            int flat = tid + it * 256;
            int r = flat >> 3, c4 = flat & 7;
            f32x4 v = *(const f32x4*)&Am[(size_t)(tr * 64 + r) * 256 + kb * 32 + c4 * 4];
            *(f32x4*)&As[r * 36 + c4 * 4] = v;
        }
        #pragma unroll
        for (int it = 0; it < 2; it++) {       // B: 32x64 = 512 float4
            int flat = tid + it * 256;
            int r = flat >> 4, c4 = flat & 15;
            f32x4 v = *(const f32x4*)&Bm[(size_t)(kb * 32 + r) * 256 + tc * 64 + c4 * 4];
            *(f32x4*)&Bs[r * 64 + c4 * 4] = v;
        }
        __syncthreads();
        #pragma unroll 8
        for (int kk = 0; kk < 32; kk++) {
            f32x4 bv = *(const f32x4*)&Bs[kk * 64 + tx * 4];
            float a0 = As[(ty * 4 + 0) * 36 + kk];
            float a1 = As[(ty * 4 + 1) * 36 + kk];
            float a2 = As[(ty * 4 + 2) * 36 + kk];
            float a3 = As[(ty * 4 + 3) * 36 + kk];
            #pragma unroll
            for (int j = 0; j < 4; j++) {
                acc[0][j] += a0 * bv[j];
                acc[1][j] += a1 * bv[j];
                acc[2][j] += a2 * bv[j];
                acc[3][j] += a3 * bv[j];
            }
        }
    }
    #pragma unroll
    for (int i = 0; i < 4; i++) {
        f32x4 v = { acc[i][0], acc[i][1], acc[i][2], acc[i][3] };
        *(f32x4*)&Dm[(size_t)(tr * 64 + ty * 4 + i) * 256 + tc * 64 + tx * 4] = v;
    }
}

// ---------------- kernel 3: AT/BT = M2 @ diag(cos|sin(phases)) @ M1 -> bf16 -
__global__ __launch_bounds__(256) void k_abt(const float* __restrict__ mats,
                                             const float* __restrict__ phases,
                                             unsigned short* __restrict__ abt) {
    const float* Am = mats + 65536;    // M2
    const float* Bm = mats;            // M1
    const int v = blockIdx.y;          // 0: cos (AT), 1: sin (BT)
    const int tr = blockIdx.x >> 2, tc = blockIdx.x & 3;

    __shared__ float As[64 * 36];
    __shared__ float Bs[32 * 64];
    const int tid = threadIdx.x;
    const int tx = tid & 15, ty = tid >> 4;

    float acc[4][4] = {};
    for (int kb = 0; kb < 8; kb++) {
        __syncthreads();
        #pragma unroll
        for (int it = 0; it < 2; it++) {
            int flat = tid + it * 256;
            int r = flat >> 3, c4 = flat & 7;
            f32x4 vv = *(const f32x4*)&Am[(size_t)(tr * 64 + r) * 256 + kb * 32 + c4 * 4];
            *(f32x4*)&As[r * 36 + c4 * 4] = vv;
        }
        #pragma unroll
        for (int it = 0; it < 2; it++) {
            int flat = tid + it * 256;
            int r = flat >> 4, c4 = flat & 15;
            int kg = kb * 32 + r;
            float ph = phases[kg];
            float sc = v ? sinf(ph) : cosf(ph);
            f32x4 vv = *(const f32x4*)&Bm[(size_t)kg * 256 + tc * 64 + c4 * 4];
            vv[0] *= sc; vv[1] *= sc; vv[2] *= sc; vv[3] *= sc;
            *(f32x4*)&Bs[r * 64 + c4 * 4] = vv;
        }
        __syncthreads();
        #pragma unroll 8
        for (int kk = 0; kk < 32; kk++) {
            f32x4 bv = *(const f32x4*)&Bs[kk * 64 + tx * 4];
            float a0 = As[(ty * 4 + 0) * 36 + kk];
            float a1 = As[(ty * 4 + 1) * 36 + kk];
            float a2 = As[(ty * 4 + 2) * 36 + kk];
            float a3 = As[(ty * 4 + 3) * 36 + kk];
            #pragma unroll
            for (int j = 0; j < 4; j++) {
                acc[0][j] += a0 * bv[j];
                acc[1][j] += a1 * bv[j];
                acc[2][j] += a2 * bv[j];
                acc[3][j] += a3 * bv[j];
            }
        }
    }
    #pragma unroll
    for (int i = 0; i < 4; i++) {
        unsigned short h0 = f2bf(acc[i][0]), h1 = f2bf(acc[i][1]);
        unsigned short h2 = f2bf(acc[i][2]), h3 = f2bf(acc[i][3]);
        u32x2 pk = { (unsigned)h0 | ((unsigned)h1 << 16),
                     (unsigned)h2 | ((unsigned)h3 << 16) };
        *(u32x2*)&abt[(size_t)(v * 256 + tr * 64 + ty * 4 + i) * 256 + tc * 64 + tx * 4] = pk;
    }
}

// ---------------- kernel 4a: normalize rows -> bf16 (fast path) -------------
__global__ __launch_bounds__(256) void k_xnorm(const float* __restrict__ x,
                                               unsigned short* __restrict__ xbf) {
    const int row = blockIdx.x * 4 + (threadIdx.x >> 6);
    const int lane = threadIdx.x & 63;
    f32x4 v = *(const f32x4*)&x[(size_t)row * 256 + lane * 4];
    float s = v[0] * v[0] + v[1] * v[1] + v[2] * v[2] + v[3] * v[3];
    for (int off = 32; off; off >>= 1) s += __shfl_xor(s, off, 64);
    float sc = 1.0f / sqrtf(s);
    unsigned short h0 = f2bf(v[0] * sc), h1 = f2bf(v[1] * sc);
    unsigned short h2 = f2bf(v[2] * sc), h3 = f2bf(v[3] * sc);
    u32x2 pk = { (unsigned)h0 | ((unsigned)h1 << 16),
                 (unsigned)h2 | ((unsigned)h3 << 16) };
    *(u32x2*)&xbf[(size_t)row * 256 + lane * 4] = pk;
}

// ---------------- kernel 4b: per-row 1/||x|| (fallback path) ----------------
__global__ __launch_bounds__(256) void k_norm(const float* __restrict__ x,
                                              float* __restrict__ invn) {
    const int row = blockIdx.x * 4 + (threadIdx.x >> 6);
    const int lane = threadIdx.x & 63;
    f32x4 v = *(const f32x4*)&x[(size_t)row * 256 + lane * 4];
    float s = v[0] * v[0] + v[1] * v[1] + v[2] * v[2] + v[3] * v[3];
    for (int off = 32; off; off >>= 1) s += __shfl_xor(s, off, 64);
    if (lane == 0) invn[row] = 1.0f / sqrtf(s);
}

// ---------------- kernel 5a: GEMM + |.|^2 from pre-converted bf16 x ---------
// Grid (cb=4, rb=512), cb minor: the 4 cb WGs sharing an x-tile dispatch
// back-to-back -> concurrent -> x served from L2/L3 after first touch.
// kb=1 tiles are prefetched into registers while kb=0 MFMAs run.
#define BKP 136   // padded LDS k-stride (bf16 elems)
__global__ __launch_bounds__(256) void k_gemm_bf(const unsigned short* __restrict__ xbf,
                                                 const unsigned short* __restrict__ abt,
                                                 float* __restrict__ out) {
    __shared__ unsigned short As[128 * BKP];
    __shared__ unsigned short Bs[128 * BKP];
    const int tid = threadIdx.x;
    const int cb = blockIdx.x;          // 0..3  (64 out-cols each)
    const int rb = blockIdx.y;          // 0..511
    const int lane = tid & 63, w = tid >> 6;

    f32x4 acc[16];
    #pragma unroll
    for (int i = 0; i < 16; i++) acc[i] = (f32x4){0.f, 0.f, 0.f, 0.f};

    int rA[8], cA[8], grB[8];
    #pragma unroll
    for (int it = 0; it < 8; it++) {
        int flat = tid + it * 256;
        rA[it] = flat >> 4; cA[it] = flat & 15;
        int r = rA[it];
        grB[it] = (r < 64) ? (cb * 64 + r) : (256 + cb * 64 + (r - 64));
    }

    u32x4 pa[8], pb[8];
    // load kb=0 tiles
    #pragma unroll
    for (int it = 0; it < 8; it++) {
        pa[it] = *(const u32x4*)&xbf[(size_t)(rb * 128 + rA[it]) * 256 + cA[it] * 8];
        pb[it] = *(const u32x4*)&abt[(size_t)grB[it] * 256 + cA[it] * 8];
    }
    #pragma unroll
    for (int it = 0; it < 8; it++) {
        *(u32x4*)&As[rA[it] * BKP + cA[it] * 8] = pa[it];
        *(u32x4*)&Bs[rA[it] * BKP + cA[it] * 8] = pb[it];
    }
    __syncthreads();
    // issue kb=1 loads (in flight during kb=0 compute)
    #pragma unroll
    for (int it = 0; it < 8; it++) {
        pa[it] = *(const u32x4*)&xbf[(size_t)(rb * 128 + rA[it]) * 256 + 128 + cA[it] * 8];
        pb[it] = *(const u32x4*)&abt[(size_t)grB[it] * 256 + 128 + cA[it] * 8];
    }

    auto compute = [&]() {
        #pragma unroll
        for (int ks = 0; ks < 4; ks++) {
            const int k0 = ks * 32 + (lane >> 4) * 8;
            s16x8 a[2], b[8];
            #pragma unroll
            for (int tm = 0; tm < 2; tm++)
                a[tm] = *(const s16x8*)&As[(w * 32 + tm * 16 + (lane & 15)) * BKP + k0];
            #pragma unroll
            for (int tn = 0; tn < 8; tn++)
                b[tn] = *(const s16x8*)&Bs[(tn * 16 + (lane & 15)) * BKP + k0];
            #pragma unroll
            for (int tm = 0; tm < 2; tm++)
                #pragma unroll
                for (int tn = 0; tn < 8; tn++)
                    acc[tm * 8 + tn] = __builtin_amdgcn_mfma_f32_16x16x32_bf16(
                        a[tm], b[tn], acc[tm * 8 + tn], 0, 0, 0);
        }
    };
    compute();                 // kb=0
    __syncthreads();
    #pragma unroll
    for (int it = 0; it < 8; it++) {
        *(u32x4*)&As[rA[it] * BKP + cA[it] * 8] = pa[it];
        *(u32x4*)&Bs[rA[it] * BKP + cA[it] * 8] = pb[it];
    }
    __syncthreads();
    compute();                 // kb=1

    // epilogue: C/D layout col = lane&15, row = (lane>>4)*4 + reg
    const int qr = lane >> 4, c = lane & 15;
    #pragma unroll
    for (int tm = 0; tm < 2; tm++) {
        #pragma unroll
        for (int tn = 0; tn < 4; tn++) {
            f32x4 p = acc[tm * 8 + tn];
            f32x4 q = acc[tm * 8 + tn + 4];
            #pragma unroll
            for (int r = 0; r < 4; r++) {
                int m = w * 32 + tm * 16 + qr * 4 + r;
                out[(size_t)(rb * 128 + m) * 256 + cb * 64 + tn * 16 + c] =
                    p[r] * p[r] + q[r] * q[r];
            }
        }
    }
}

// ---------------- kernel 5b: GEMM + |.|^2 from fp32 x (fallback) ------------
__global__ __launch_bounds__(256) void k_gemm_f32(const float* __restrict__ x,
                                                  const unsigned short* __restrict__ abt,
                                                  const float* __restrict__ invn,
                                                  float* __restrict__ out) {
    __shared__ unsigned short As[128 * BKP];
    __shared__ unsigned short Bs[128 * BKP];
    const int tid = threadIdx.x;
    const int cb = blockIdx.x;
    const int rb = blockIdx.y;
    const int lane = tid & 63, w = tid >> 6;

    f32x4 acc[16];
    #pragma unroll
    for (int i = 0; i < 16; i++) acc[i] = (f32x4){0.f, 0.f, 0.f, 0.f};

    for (int kb = 0; kb < 2; kb++) {
        __syncthreads();
        #pragma unroll
        for (int it = 0; it < 16; it++) {
            int flat = tid + it * 256;
            int r = flat >> 5, c4 = flat & 31;
            f32x4 v = *(const f32x4*)&x[(size_t)(rb * 128 + r) * 256 + kb * 128 + c4 * 4];
            float sc = invn[rb * 128 + r];
            v[0] *= sc; v[1] *= sc; v[2] *= sc; v[3] *= sc;
            unsigned short h0 = f2bf(v[0]), h1 = f2bf(v[1]);
            unsigned short h2 = f2bf(v[2]), h3 = f2bf(v[3]);
            u32x2 pk = { (unsigned)h0 | ((unsigned)h1 << 16),
                         (unsigned)h2 | ((unsigned)h3 << 16) };
            *(u32x2*)&As[r * BKP + c4 * 4] = pk;
        }
        #pragma unroll
        for (int it = 0; it < 8; it++) {
            int flat = tid + it * 256;
            int r = flat >> 4, c8 = flat & 15;
            int gr = (r < 64) ? (cb * 64 + r) : (256 + cb * 64 + (r - 64));
            u32x4 vv = *(const u32x4*)&abt[(size_t)gr * 256 + kb * 128 + c8 * 8];
            *(u32x4*)&Bs[r * BKP + c8 * 8] = vv;
        }
        __syncthreads();
        #pragma unroll
        for (int ks = 0; ks < 4; ks++) {
            const int k0 = ks * 32 + (lane >> 4) * 8;
            s16x8 a[2], b[8];
            #pragma unroll
            for (int tm = 0; tm < 2; tm++)
                a[tm] = *(const s16x8*)&As[(w * 32 + tm * 16 + (lane & 15)) * BKP + k0];
            #pragma unroll
            for (int tn = 0; tn < 8; tn++)
                b[tn] = *(const s16x8*)&Bs[(tn * 16 + (lane & 15)) * BKP + k0];
            #pragma unroll
            for (int tm = 0; tm < 2; tm++)
                #pragma unroll
                for (int tn = 0; tn < 8; tn++)
                    acc[tm * 8 + tn] = __builtin_amdgcn_mfma_f32_16x16x32_bf16(
                        a[tm], b[tn], acc[tm * 8 + tn], 0, 0, 0);
        }
    }

    const int qr = lane >> 4, c = lane & 15;
    #pragma unroll
    for (int tm = 0; tm < 2; tm++) {
        #pragma unroll
        for (int tn = 0; tn < 4; tn++) {
            f32x4 p = acc[tm * 8 + tn];
            f32x4 q = acc[tm * 8 + tn + 4];
            #pragma unroll
            for (int r = 0; r < 4; r++) {
                int m = w * 32 + tm * 16 + qr * 4 + r;
                out[(size_t)(rb * 128 + m) * 256 + cb * 64 + tn * 16 + c] =
                    p[r] * p[r] + q[r] * q[r];
            }
        }
    }
}

// ---------------- host ------------------------------------------------------
extern "C" void kernel_launch(void* const* d_in, const int* in_sizes, int n_in,
                              void* d_out, int out_size, void* d_ws, size_t ws_size,
                              hipStream_t stream) {
    (void)in_sizes; (void)n_in; (void)out_size;
    const float* x      = (const float*)d_in[0];
    const float* rots1  = (const float*)d_in[1];
    const float* phases = (const float*)d_in[2];
    const float* rots2  = (const float*)d_in[3];
    float* out = (float*)d_out;
    char* ws = (char*)d_ws;

    const size_t MAT = 262144;                 // 256x256 fp32
    int pblk = 32;
    while (pblk > 16 &&
           (size_t)3 * pblk * MAT + 2 * MAT + (size_t)BATCH * 512 > ws_size)
        pblk >>= 1;
    const size_t offA   = 0;
    const size_t offB   = offA + (size_t)2 * pblk * MAT;   // A: 2*pblk mats
    const size_t offABT = offB + (size_t)pblk * MAT;       // B: pblk mats
    const size_t offINV = offABT + MAT;
    const size_t offXBF = offINV + MAT;
    const bool use_xbf = (offXBF + (size_t)BATCH * 512) <= ws_size;

    float*          A    = (float*)(ws + offA);
    float*          B    = (float*)(ws + offB);
    unsigned short* abt  = (unsigned short*)(ws + offABT);
    float*          invn = (float*)(ws + offINV);
    unsigned short* xbf  = (unsigned short*)(ws + offXBF);

    k_blocks<<<dim3(4, pblk, 2), 64, 0, stream>>>(rots1, rots2, A, pblk);

    float* srcp = A; float* dstp = B;
    for (int half = pblk / 2; half >= 1; half >>= 1) {
        k_combine<<<dim3(16, 2 * half), 256, 0, stream>>>(srcp, dstp, half, pblk);
        float* tmp = srcp; srcp = dstp; dstp = tmp;
    }
    k_abt<<<dim3(16, 2), 256, 0, stream>>>(srcp, phases, abt);

    if (use_xbf) {
        k_xnorm<<<BATCH / 4, 256, 0, stream>>>(x, xbf);
        k_gemm_bf<<<dim3(4, BATCH / 128), 256, 0, stream>>>(xbf, abt, out);
    } else {
        k_norm<<<BATCH / 4, 256, 0, stream>>>(x, invn);
        k_gemm_f32<<<dim3(4, BATCH / 128), 256, 0, stream>>>(x, abt, invn, out);
    }
}